// Round 1
// 940.853 us; speedup vs baseline: 1.2265x; 1.2265x over previous
//
#include <hip/hip_runtime.h>
#include <cstdint>
#include <cstddef>

// MultiHeadAttention: B=2, N=2048, EMB=2048, H=8, D=256.  fp32 I/O.
// R6: 621 us attn, latency-serialized (MfmaUtil 9.2, VALU 13.5, HBM 7.4 --
// all idle; 2 barriers + full softmax + exposed staging latency per 32 kv).
// R7: kv-tile 64; K hi/lo staged via global_load_lds with XOR-swizzled
// per-lane global source (linear LDS dest, swizzled ds_read -- conflict-free
// at the 8/bank floor); stage issue moved after the post-QK barrier so load
// latency hides under softmax+PV; V read directly from global (L2-resident,
// 1 MB/bh; 4 waves share fragments via L1) -- LDS = 74.7 KB, 2 blocks/CU;
// setprio(1) around MFMA clusters.
// ws (96 MiB): qh 16 | ql 16 | kh 16 | kl 16 | vT 16 | attn 16 ;
// wprojT aliases qh after attention.

typedef __bf16 bf16x8 __attribute__((ext_vector_type(8)));
typedef __bf16 bf16x2 __attribute__((ext_vector_type(2)));
typedef float f32x4 __attribute__((ext_vector_type(4)));

#define SCALE_INV 0.022097086912079608f  // 1/sqrt(2048)

__device__ inline void split8(const float4 v0, const float4 v1, bf16x8& hi,
                              bf16x8& lo) {
  float a[8] = {v0.x, v0.y, v0.z, v0.w, v1.x, v1.y, v1.z, v1.w};
  bf16x8 h, l;
#pragma unroll
  for (int i = 0; i < 8; i++) {
    __bf16 hh = (__bf16)a[i];
    h[i] = hh;
    l[i] = (__bf16)(a[i] - (float)hh);
  }
  hi = h;
  lo = l;
}

// out[c][r] = (bf16) in[r][c]
__global__ __launch_bounds__(256) void transpose_cvt_k(
    const float* __restrict__ in, __bf16* __restrict__ out, int R, int C) {
  __shared__ float tile[32][33];
  const int tx = threadIdx.x & 31;
  const int ty = threadIdx.x >> 5;
  const int c0 = blockIdx.x * 32;
  const int r0 = blockIdx.y * 32;
#pragma unroll
  for (int i = 0; i < 32; i += 8)
    tile[ty + i][tx] = in[(size_t)(r0 + ty + i) * C + (c0 + tx)];
  __syncthreads();
#pragma unroll
  for (int i = 0; i < 32; i += 8)
    out[(size_t)(c0 + ty + i) * R + (r0 + tx)] = (__bf16)tile[tx][ty + i];
}

// QKV GEMM, split-bf16 3-pass.  A = X fp32 [4096][2048] row-major.
// B = W fp32 [2048][6144] row-major (transposed during LDS staging).
// Scatter: col = h*768 + d*3 + c -> qh/ql, kh/kl (bf16 hi/lo pairs), vT bf16.
__global__ __launch_bounds__(256) void gemm_qkv_split_k(
    const float* __restrict__ X, const float* __restrict__ W,
    const float* __restrict__ bias, __bf16* __restrict__ qh_,
    __bf16* __restrict__ ql_, __bf16* __restrict__ kh_,
    __bf16* __restrict__ kl_, __bf16* __restrict__ vT) {
  __shared__ __bf16 Ah[128 * 40], Al[128 * 40];
  __shared__ __bf16 Bh[128 * 40], Bl[128 * 40];
  const int tid = threadIdx.x, lane = tid & 63, wave = tid >> 6;
  const int l16 = lane & 15, quad = lane >> 4;
  const int wm = (wave >> 1) * 64, wn = (wave & 1) * 64;
  const int m0 = blockIdx.y * 128, n0 = blockIdx.x * 128;
  const int r0 = tid >> 2, kc0 = (tid & 3) * 8;
  const int bn = tid & 31;        // B-staging: base n (coalesced)
  const int bk = (tid >> 5) * 2;  // B-staging: even k in [0,16)

  f32x4 zero4 = {0.f, 0.f, 0.f, 0.f};
  f32x4 acc[4][4];
#pragma unroll
  for (int i = 0; i < 4; i++)
#pragma unroll
    for (int j = 0; j < 4; j++) acc[i][j] = zero4;

  const float* Arow0 = X + (size_t)(m0 + r0) * 2048 + kc0;
  const float* Arow1 = Arow0 + (size_t)64 * 2048;

  for (int k0 = 0; k0 < 2048; k0 += 32) {
    float4 a00 = *(const float4*)(Arow0 + k0);
    float4 a01 = *(const float4*)(Arow0 + k0 + 4);
    float4 a10 = *(const float4*)(Arow1 + k0);
    float4 a11 = *(const float4*)(Arow1 + k0 + 4);
    float wv[2][4][2];
#pragma unroll
    for (int p = 0; p < 2; p++) {
      const int kk = k0 + p * 16 + bk;
#pragma unroll
      for (int i = 0; i < 4; i++) {
        const int nn = n0 + bn + 32 * i;
        wv[p][i][0] = W[(size_t)kk * 6144 + nn];
        wv[p][i][1] = W[(size_t)(kk + 1) * 6144 + nn];
      }
    }
    bf16x8 ah0, al0, ah1, al1;
    split8(a00, a01, ah0, al0);
    split8(a10, a11, ah1, al1);
    __syncthreads();
    *(bf16x8*)&Ah[r0 * 40 + kc0] = ah0;
    *(bf16x8*)&Al[r0 * 40 + kc0] = al0;
    *(bf16x8*)&Ah[(r0 + 64) * 40 + kc0] = ah1;
    *(bf16x8*)&Al[(r0 + 64) * 40 + kc0] = al1;
#pragma unroll
    for (int p = 0; p < 2; p++) {
      const int kk = p * 16 + bk;
#pragma unroll
      for (int i = 0; i < 4; i++) {
        const int nn = bn + 32 * i;
        const float a = wv[p][i][0], b = wv[p][i][1];
        __bf16 h0 = (__bf16)a, h1 = (__bf16)b;
        bf16x2 h = {h0, h1};
        bf16x2 l = {(__bf16)(a - (float)h0), (__bf16)(b - (float)h1)};
        *(bf16x2*)&Bh[nn * 40 + kk] = h;
        *(bf16x2*)&Bl[nn * 40 + kk] = l;
      }
    }
    __syncthreads();
    bf16x8 fah[4], fal[4], fbh[4], fbl[4];
#pragma unroll
    for (int i = 0; i < 4; i++) {
      fah[i] = *(const bf16x8*)&Ah[(wm + i * 16 + l16) * 40 + quad * 8];
      fal[i] = *(const bf16x8*)&Al[(wm + i * 16 + l16) * 40 + quad * 8];
    }
#pragma unroll
    for (int j = 0; j < 4; j++) {
      fbh[j] = *(const bf16x8*)&Bh[(wn + j * 16 + l16) * 40 + quad * 8];
      fbl[j] = *(const bf16x8*)&Bl[(wn + j * 16 + l16) * 40 + quad * 8];
    }
#pragma unroll
    for (int i = 0; i < 4; i++)
#pragma unroll
      for (int j = 0; j < 4; j++) {
        acc[i][j] = __builtin_amdgcn_mfma_f32_16x16x32_bf16(fah[i], fbh[j],
                                                            acc[i][j], 0, 0, 0);
        acc[i][j] = __builtin_amdgcn_mfma_f32_16x16x32_bf16(fah[i], fbl[j],
                                                            acc[i][j], 0, 0, 0);
        acc[i][j] = __builtin_amdgcn_mfma_f32_16x16x32_bf16(fal[i], fbh[j],
                                                            acc[i][j], 0, 0, 0);
      }
  }

#pragma unroll
  for (int i = 0; i < 4; i++) {
#pragma unroll
    for (int j = 0; j < 4; j++) {
      const int col = n0 + wn + j * 16 + l16;
      const float bv = bias[col];
      const int h = col / 768;
      const int rr = col - h * 768;
      const int d = rr / 3;
      const int c = rr - d * 3;
#pragma unroll
      for (int r = 0; r < 4; r++) {
        const int row = m0 + wm + i * 16 + quad * 4 + r;
        const float v = acc[i][j][r] + bv;
        const int b = row >> 11;
        const int nn = row & 2047;
        const int bh = b * 8 + h;
        const size_t idx = ((size_t)bh * 2048 + nn) * 256 + d;
        if (c == 0) {
          __bf16 hi = (__bf16)v;
          qh_[idx] = hi;
          ql_[idx] = (__bf16)(v - (float)hi);
        } else if (c == 1) {
          __bf16 hi = (__bf16)v;
          kh_[idx] = hi;
          kl_[idx] = (__bf16)(v - (float)hi);
        } else {
          vT[((size_t)bh * 256 + d) * 2048 + nn] = (__bf16)v;
        }
      }
    }
  }
}

// Direct global->LDS 16B DMA (per-lane global src, wave-uniform LDS dest).
#define GLDS16(gp, lp)                                                        \
  __builtin_amdgcn_global_load_lds(                                           \
      (const __attribute__((address_space(1))) void*)(gp),                    \
      (__attribute__((address_space(3))) void*)(lp), 16, 0, 0)

// Flash attention, kv-tile 64.  Q/K hi/lo bf16 pairs.
// K hi/lo in LDS, linear [64][256] with XOR swizzle (byte ^= (row&7)<<4):
// staged by global_load_lds with pre-swizzled per-lane source, read with
// swizzled ds_read -- both at the 8-access/bank floor.  V read directly from
// global (L2-resident).  Stage for tile i+1 issued after the post-QK barrier
// of tile i, hidden under softmax+PV.
__global__ __launch_bounds__(256, 2) void attn_fwd_k(
    const __bf16* __restrict__ Qh,  // [16][2048][256]
    const __bf16* __restrict__ Ql,
    const __bf16* __restrict__ Kh,
    const __bf16* __restrict__ Kl,
    const __bf16* __restrict__ Vt,  // [16][256][2048]
    __bf16* __restrict__ out) {     // [2][2048][2048] (b, n, h*256+d)
  __shared__ __attribute__((aligned(16))) __bf16 KhL[64 * 256];  // 32 KB
  __shared__ __attribute__((aligned(16))) __bf16 KlL[64 * 256];  // 32 KB
  __shared__ __attribute__((aligned(16))) __bf16 Plds[4][16 * 72];  // 9 KB

  const int qblk = blockIdx.x;
  const int bh = blockIdx.y;
  const int bb = bh >> 3, hh = bh & 7;
  const int tid = threadIdx.x, lane = tid & 63, wave = tid >> 6;
  const int l16 = lane & 15, quad = lane >> 4;

  const size_t hqk = (size_t)bh * 2048 * 256;
  const __bf16* qhp = Qh + hqk;
  const __bf16* qlp = Ql + hqk;
  const __bf16* khp = Kh + hqk;
  const __bf16* klp = Kl + hqk;
  const __bf16* vp = Vt + (size_t)bh * 256 * 2048;

  const int qrow = qblk * 64 + wave * 16;

  bf16x8 qhf[8], qlf[8];
#pragma unroll
  for (int t = 0; t < 8; t++) {
    const size_t off = (size_t)(qrow + l16) * 256 + t * 32 + quad * 8;
    qhf[t] = *(const bf16x8*)&qhp[off];
    qlf[t] = *(const bf16x8*)&qlp[off];
  }

  f32x4 zero4 = {0.f, 0.f, 0.f, 0.f};
  f32x4 o[16];
#pragma unroll
  for (int dt = 0; dt < 16; dt++) o[dt] = zero4;
  float mrow[4], lrow[4];
#pragma unroll
  for (int r = 0; r < 4; r++) {
    mrow[r] = -3.0e38f;
    lrow[r] = 0.f;
  }

  // Staging geometry: wave w stages tile rows [w*16, w*16+16) of both K
  // arrays; instruction i covers 2 rows (1024 B).  Lane source offset is
  // pre-swizzled so the linear LDS write yields the swizzled layout:
  //   stored(row, cb) = K[row][cb ^ ((row&7)<<4)]  (cb = byte-in-row).
  int koff[8];  // per-lane global elem offset within the 64x256 tile
#pragma unroll
  for (int i = 0; i < 8; i++) {
    const int r = wave * 16 + i * 2 + (lane >> 5);
    const int cb = ((lane & 31) << 4) ^ ((r & 7) << 4);
    koff[i] = r * 256 + (cb >> 1);
  }
  const int ldsb = wave * 4096;  // elems

  // prologue: stage tile 0
#pragma unroll
  for (int i = 0; i < 8; i++) {
    GLDS16(khp + koff[i], &KhL[ldsb + i * 512]);
    GLDS16(klp + koff[i], &KlL[ldsb + i * 512]);
  }

  for (int kv0 = 0; kv0 < 2048; kv0 += 64) {
    __syncthreads();  // vmcnt drain: staged K tile resident in LDS

    // S = q_tile @ k_tile^T : 4 subtiles of 16x16, split-bf16 3-pass.
    // 4 independent accumulator chains (j) for MFMA ILP.
    f32x4 s[4];
#pragma unroll
    for (int j = 0; j < 4; j++) s[j] = zero4;
    __builtin_amdgcn_s_setprio(1);
#pragma unroll
    for (int j = 0; j < 4; j++) {
      const int row = j * 16 + l16;
      const int swz = (row & 7) << 3;  // elem-granularity XOR (16B chunks)
      const int rb = row * 256;
#pragma unroll
      for (int t = 0; t < 8; t++) {
        const int off = rb + ((t * 32 + quad * 8) ^ swz);
        bf16x8 khf = *(const bf16x8*)&KhL[off];
        bf16x8 klf = *(const bf16x8*)&KlL[off];
        s[j] =
            __builtin_amdgcn_mfma_f32_16x16x32_bf16(qhf[t], khf, s[j], 0, 0, 0);
        s[j] =
            __builtin_amdgcn_mfma_f32_16x16x32_bf16(qhf[t], klf, s[j], 0, 0, 0);
        s[j] =
            __builtin_amdgcn_mfma_f32_16x16x32_bf16(qlf[t], khf, s[j], 0, 0, 0);
      }
    }
    __builtin_amdgcn_s_setprio(0);
    __syncthreads();  // all waves done reading this K tile

    // issue next tile's staging now: latency hides under softmax+PV
    if (kv0 + 64 < 2048) {
      const int kvn = (kv0 + 64) * 256;
#pragma unroll
      for (int i = 0; i < 8; i++) {
        GLDS16(khp + kvn + koff[i], &KhL[ldsb + i * 512]);
        GLDS16(klp + kvn + koff[i], &KlL[ldsb + i * 512]);
      }
    }

    // online softmax (rows quad*4+r, cols l16 of 4 kv subtiles)
    float mnew[4], alpha[4], psum[4];
#pragma unroll
    for (int r = 0; r < 4; r++) {
      float mx = fmaxf(fmaxf(s[0][r], s[1][r]), fmaxf(s[2][r], s[3][r]));
#pragma unroll
      for (int off = 1; off < 16; off <<= 1)
        mx = fmaxf(mx, __shfl_xor(mx, off, 16));
      mnew[r] = fmaxf(mrow[r], mx);
      alpha[r] = __expf(mrow[r] - mnew[r]);
      psum[r] = 0.f;
    }
#pragma unroll
    for (int j = 0; j < 4; j++)
#pragma unroll
      for (int r = 0; r < 4; r++) {
        float p = __expf(s[j][r] - mnew[r]);
        s[j][r] = p;
        psum[r] += p;
      }
#pragma unroll
    for (int r = 0; r < 4; r++) {
#pragma unroll
      for (int off = 1; off < 16; off <<= 1)
        psum[r] += __shfl_xor(psum[r], off, 16);
      lrow[r] = lrow[r] * alpha[r] + psum[r];
      mrow[r] = mnew[r];
    }
#pragma unroll
    for (int dt = 0; dt < 16; dt++) {
      o[dt][0] *= alpha[0];
      o[dt][1] *= alpha[1];
      o[dt][2] *= alpha[2];
      o[dt][3] *= alpha[3];
    }
    // P: C-layout -> per-wave LDS -> A-operand layout (no barrier needed)
#pragma unroll
    for (int j = 0; j < 4; j++)
#pragma unroll
      for (int r = 0; r < 4; r++)
        Plds[wave][(quad * 4 + r) * 72 + j * 16 + l16] = (__bf16)s[j][r];
    bf16x8 pa0 = *(const bf16x8*)&Plds[wave][l16 * 72 + quad * 8];
    bf16x8 pa1 = *(const bf16x8*)&Plds[wave][l16 * 72 + 32 + quad * 8];

    // O += P @ V, V fragments straight from global (L2/L1-resident)
    __builtin_amdgcn_s_setprio(1);
#pragma unroll
    for (int dt = 0; dt < 16; dt++) {
      const __bf16* vr = vp + (size_t)(dt * 16 + l16) * 2048 + kv0 + quad * 8;
      bf16x8 vf0 = *(const bf16x8*)vr;
      bf16x8 vf1 = *(const bf16x8*)(vr + 32);
      o[dt] = __builtin_amdgcn_mfma_f32_16x16x32_bf16(pa0, vf0, o[dt], 0, 0, 0);
      o[dt] = __builtin_amdgcn_mfma_f32_16x16x32_bf16(pa1, vf1, o[dt], 0, 0, 0);
    }
    __builtin_amdgcn_s_setprio(0);
  }

#pragma unroll
  for (int r = 0; r < 4; r++) {
    const float inv = SCALE_INV / lrow[r];
    const int n = qrow + quad * 4 + r;
    const size_t base = ((size_t)bb * 2048 + n) * 2048 + hh * 256;
#pragma unroll
    for (int dt = 0; dt < 16; dt++)
      out[base + dt * 16 + l16] = (__bf16)(o[dt][r] * inv);
  }
}

// Plain bf16 GEMM, C = A[M][K] * Bt[N][K]^T + bias, fp32 store.
__global__ __launch_bounds__(256) void gemm_bt_k(
    const __bf16* __restrict__ A, const __bf16* __restrict__ Bt,
    const float* __restrict__ bias, int M, int Ncols, int K,
    float* __restrict__ outF) {
  __shared__ __bf16 As[128 * 40];
  __shared__ __bf16 Bs[128 * 40];
  const int tid = threadIdx.x, lane = tid & 63, wave = tid >> 6;
  const int l16 = lane & 15, quad = lane >> 4;
  const int wm = (wave >> 1) * 64, wn = (wave & 1) * 64;
  const int m0 = blockIdx.y * 128, n0 = blockIdx.x * 128;
  const int r0 = tid >> 2, kc0 = (tid & 3) * 8;

  f32x4 zero4 = {0.f, 0.f, 0.f, 0.f};
  f32x4 acc[4][4];
#pragma unroll
  for (int i = 0; i < 4; i++)
#pragma unroll
    for (int j = 0; j < 4; j++) acc[i][j] = zero4;

  const __bf16* Aptr = A + (size_t)(m0 + r0) * K + kc0;
  const __bf16* Bptr = Bt + (size_t)(n0 + r0) * K + kc0;
  const size_t rowstep = (size_t)64 * K;

  for (int k0 = 0; k0 < K; k0 += 32) {
    uint4 a0 = *(const uint4*)(Aptr + k0);
    uint4 a1 = *(const uint4*)(Aptr + rowstep + k0);
    uint4 b0 = *(const uint4*)(Bptr + k0);
    uint4 b1 = *(const uint4*)(Bptr + rowstep + k0);
    __syncthreads();
    *(uint4*)&As[r0 * 40 + kc0] = a0;
    *(uint4*)&As[(r0 + 64) * 40 + kc0] = a1;
    *(uint4*)&Bs[r0 * 40 + kc0] = b0;
    *(uint4*)&Bs[(r0 + 64) * 40 + kc0] = b1;
    __syncthreads();
    bf16x8 af[4], bfv[4];
#pragma unroll
    for (int i = 0; i < 4; i++)
      af[i] = *(const bf16x8*)&As[(wm + i * 16 + l16) * 40 + quad * 8];
#pragma unroll
    for (int j = 0; j < 4; j++)
      bfv[j] = *(const bf16x8*)&Bs[(wn + j * 16 + l16) * 40 + quad * 8];
#pragma unroll
    for (int i = 0; i < 4; i++)
#pragma unroll
      for (int j = 0; j < 4; j++)
        acc[i][j] = __builtin_amdgcn_mfma_f32_16x16x32_bf16(af[i], bfv[j],
                                                            acc[i][j], 0, 0, 0);
  }

#pragma unroll
  for (int i = 0; i < 4; i++)
#pragma unroll
    for (int j = 0; j < 4; j++) {
      const int col = n0 + wn + j * 16 + l16;
      const float bv = bias[col];
#pragma unroll
      for (int r = 0; r < 4; r++) {
        const int row = m0 + wm + i * 16 + quad * 4 + r;
        outF[(size_t)row * Ncols + col] = acc[i][j][r] + bv;
      }
    }
}

extern "C" void kernel_launch(void* const* d_in, const int* in_sizes, int n_in,
                              void* d_out, int out_size, void* d_ws,
                              size_t ws_size, hipStream_t stream) {
  const float* x = (const float*)d_in[0];       // [2,2048,2048]
  const float* w_qkv = (const float*)d_in[1];   // [2048,6144]
  const float* b_qkv = (const float*)d_in[2];   // [6144]
  const float* w_proj = (const float*)d_in[3];  // [2048,2048]
  const float* b_proj = (const float*)d_in[4];  // [2048]
  float* out = (float*)d_out;                   // [2,2048,2048] fp32

  const size_t HSZ = (size_t)16 * 2048 * 256;  // 8M elems = 16 MiB bf16
  __bf16* qh = (__bf16*)d_ws;
  __bf16* ql = qh + HSZ;
  __bf16* kh = ql + HSZ;
  __bf16* kl = kh + HSZ;
  __bf16* vT = kl + HSZ;
  __bf16* attn = vT + HSZ;
  __bf16* wprojT = qh;  // aliases qh/ql region AFTER attention

  gemm_qkv_split_k<<<dim3(48, 32), 256, 0, stream>>>(x, w_qkv, b_qkv, qh, ql,
                                                     kh, kl, vT);
  attn_fwd_k<<<dim3(32, 16), 256, 0, stream>>>(qh, ql, kh, kl, vT, attn);
  transpose_cvt_k<<<dim3(64, 64), 256, 0, stream>>>(w_proj, wprojT, 2048, 2048);
  gemm_bt_k<<<dim3(16, 32), 256, 0, stream>>>(attn, wprojT, b_proj, 4096, 2048,
                                              2048, out);
}